// Round 7
// baseline (2548.241 us; speedup 1.0000x reference)
//
#include <hip/hip_runtime.h>
#include <hip/hip_fp16.h>

#define BB 16
#define NN 1024
#define DD 256

typedef _Float16 h8 __attribute__((ext_vector_type(8)));
typedef _Float16 hv4 __attribute__((ext_vector_type(4)));
typedef float f32x4 __attribute__((ext_vector_type(4)));
typedef float f32x2 __attribute__((ext_vector_type(2)));

#if __has_builtin(__builtin_amdgcn_exp2f)
#define EXP2F(x) __builtin_amdgcn_exp2f(x)
#else
#define EXP2F(x) exp2f(x)
#endif
#if __has_builtin(__builtin_amdgcn_logf)
#define LOG2F(x) __builtin_amdgcn_logf(x)
#else
#define LOG2F(x) log2f(x)
#endif

// log2-domain: A2s = -100*log2e*relu(1-S) - CPOS2*|i-j|   (pos prior folded in, fp16)
constexpr float K_A2  = -144.26950408889634f;                 // -100*log2(e)
constexpr float CPOS2 = (float)(0.2 * 1.4426950408889634 / 1023.0);
constexpr float C1    = 0.06931471805599453f;                 // ln2/10 : C_content = -C1*A2content
constexpr float BASE2 = -10.0f;                               // log2(1/1024 + 1e-12)

// padded LDS index: stride-9 kills the 16-way bank conflicts of stride-8
#define PIDX(i) ((i) + ((i) >> 3))

__device__ __forceinline__ float waveReduceSum(float v) {
#pragma unroll
  for (int o = 32; o; o >>= 1) v += __shfl_xor(v, o);
  return v;
}

// Pinned 16-byte load: inline asm so the compiler CANNOT rematerialize (re-load)
// the value inside the sinkhorn loop. Waitcnt embedded -> result valid on return.
__device__ __forceinline__ h8 lda16(const _Float16* p) {
  f32x4 r;
  asm volatile("global_load_dwordx4 %0, %1, off\n\ts_waitcnt vmcnt(0)"
               : "=v"(r) : "v"(p) : "memory");
  return __builtin_bit_cast(h8, r);
}

// Coherent-point (cache-bypassing) primitives for cross-XCD exchange.
__device__ __forceinline__ void st_cv(float* p, float v) {
  asm volatile("global_store_dword %0, %1, off sc0 sc1" :: "v"(p), "v"(v) : "memory");
}
__device__ __forceinline__ void stu_cv(unsigned* p, unsigned v) {
  asm volatile("global_store_dword %0, %1, off sc0 sc1" :: "v"(p), "v"(v) : "memory");
}
__device__ __forceinline__ unsigned ldu_cv(const unsigned* p) {
  unsigned r;
  asm volatile("global_load_dword %0, %1, off sc0 sc1\n\ts_waitcnt vmcnt(0)"
               : "=v"(r) : "v"(p) : "memory");
  return r;
}
__device__ __forceinline__ f32x2 ld2_cv(const float* p) {
  f32x2 r;
  asm volatile("global_load_dwordx2 %0, %1, off sc0 sc1\n\ts_waitcnt vmcnt(0)"
               : "=v"(r) : "v"(p) : "memory");
  return r;
}

// ---------------- K1: normalize rows of X and Y -> fp16 ----------------
__global__ __launch_bounds__(256) void normalize_kernel(
    const float* __restrict__ X, const float* __restrict__ Y,
    _Float16* __restrict__ Xh, _Float16* __restrict__ Yh) {
  int wave = threadIdx.x >> 6;
  int lane = threadIdx.x & 63;
  int row = blockIdx.x * 4 + wave;           // 0 .. 2*BB*NN-1
  const float* src;
  _Float16* dst;
  if (row < BB * NN) { src = X + (size_t)row * DD; dst = Xh + (size_t)row * DD; }
  else { int r2 = row - BB * NN; src = Y + (size_t)r2 * DD; dst = Yh + (size_t)r2 * DD; }
  float4 v = *(const float4*)(src + lane * 4);
  float ss = v.x * v.x + v.y * v.y + v.z * v.z + v.w * v.w;
  ss = waveReduceSum(ss);
  float sc = 1.0f / fmaxf(sqrtf(ss), 1e-12f);
  hv4 hv;
  hv[0] = (_Float16)(v.x * sc); hv[1] = (_Float16)(v.y * sc);
  hv[2] = (_Float16)(v.z * sc); hv[3] = (_Float16)(v.w * sc);
  *(hv4*)(dst + lane * 4) = hv;
}

// ---------------- K2: S = Ah . Bh^T per batch, write A2s (content+pos, fp16) ----
__global__ __launch_bounds__(256) void gemm_a2_kernel(
    const _Float16* __restrict__ Ah, const _Float16* __restrict__ Bh,
    _Float16* __restrict__ Out) {
  const int b = blockIdx.z;
  const int I0 = blockIdx.y * 128;
  const int J0 = blockIdx.x * 128;
  const int lane = threadIdx.x & 63;
  const int wave = threadIdx.x >> 6;
  const int m = lane & 15, quad = lane >> 4;
  const _Float16* Abase = Ah + ((size_t)b * NN + I0 + wave * 32) * DD;
  const _Float16* Bbase = Bh + ((size_t)b * NN + J0) * DD;
  f32x4 acc[2][8] = {};
  for (int k0 = 0; k0 < DD; k0 += 32) {
    int koff = k0 + quad * 8;
    h8 a0 = *(const h8*)(Abase + (size_t)m * DD + koff);
    h8 a1 = *(const h8*)(Abase + (size_t)(m + 16) * DD + koff);
#pragma unroll
    for (int t = 0; t < 8; ++t) {
      h8 bf = *(const h8*)(Bbase + (size_t)(t * 16 + m) * DD + koff);
      acc[0][t] = __builtin_amdgcn_mfma_f32_16x16x32_f16(a0, bf, acc[0][t], 0, 0, 0);
      acc[1][t] = __builtin_amdgcn_mfma_f32_16x16x32_f16(a1, bf, acc[1][t], 0, 0, 0);
    }
  }
  _Float16* Ob = Out + ((size_t)b * NN + I0 + wave * 32) * NN + J0;
#pragma unroll
  for (int a = 0; a < 2; ++a)
#pragma unroll
    for (int t = 0; t < 8; ++t)
#pragma unroll
      for (int r = 0; r < 4; ++r) {
        int row = a * 16 + quad * 4 + r;
        int col = t * 16 + m;
        float s = acc[a][t][r];
        float ri = (float)(I0 + wave * 32 + row);
        float ci = (float)(J0 + col);
        Ob[(size_t)row * NN + col] =
            (_Float16)(K_A2 * fmaxf(1.0f - s, 0.0f) - CPOS2 * fabsf(ri - ci));
      }
}

// ---------------- Sinkhorn: flag-synchronized persistent kernel ----------------
// Sync and data are SEPARATE (round 6's fused {value,epoch} pairs made every
// poll retry re-read 8 KB -> 966 MB of coherent-point fetch = the bottleneck).
//  - values: plain float arrays, written uncached (sc0 sc1), loaded ONCE per
//    phase per block with contiguous dwordx2 (4 KB).
//  - flags: one 64B line per batch (16 dwords, one per producer block), each
//    written after that block's value stores drain. Consumers poll the single
//    line with one wave-coalesced load (lane&15) -> 64 B per poll.
// Epochs are monotonic; overwrite-safety by dataflow (a block publishes epoch
// e+1 only after consuming e, which requires all peers' flags >= e).

__device__ __forceinline__ void waitFlags(const unsigned* flagLine, unsigned target,
                                          int lane) {
  const unsigned* p = flagLine + (lane & 15);
  while (true) {
    unsigned v = ldu_cv(p);
    if (__ballot(v >= target) == ~0ull) break;
    __builtin_amdgcn_s_sleep(1);
  }
}

// thread t stages values[2t..2t+1] -> padded LDS
__device__ __forceinline__ void stageVals(float* lds, const float* __restrict__ src,
                                          int t) {
  f32x2 v = ld2_cv(src + 2 * t);
  int i = 2 * t;
  lds[PIDX(i)] = v[0];
  lds[PIDX(i + 1)] = v[1];
}

__device__ __forceinline__ void ldsVec16p(const float* lds, int j0, float (&out)[16]) {
#pragma unroll
  for (int k = 0; k < 8; ++k) {
    out[k] = lds[PIDX(j0 + k)];
    out[8 + k] = lds[PIDX(512 + j0 + k)];
  }
}

__device__ __forceinline__ float lseRow(const h8 (&rw)[2], const float (&gv)[16]) {
  float x[16];
#pragma unroll
  for (int k = 0; k < 8; ++k) {
    x[k]     = (float)rw[0][k] + gv[k];
    x[8 + k] = (float)rw[1][k] + gv[8 + k];
  }
  float m = x[0];
#pragma unroll
  for (int k = 1; k < 16; ++k) m = fmaxf(m, x[k]);
#pragma unroll
  for (int o = 32; o; o >>= 1) m = fmaxf(m, __shfl_xor(m, o));
  float s = 0.f;
#pragma unroll
  for (int k = 0; k < 16; ++k) s += EXP2F(x[k] - m);
  s = waveReduceSum(s);
  return BASE2 - (m + LOG2F(s));
}

// lanes 0..7 publish the wave's 8 contiguous row-results with uncached dwords
__device__ __forceinline__ void storeRows(float* vals, int r0, const float (&rs)[8],
                                          int lane) {
  if (lane < 8) {
    float v = rs[0];
    v = lane == 1 ? rs[1] : v;
    v = lane == 2 ? rs[2] : v;
    v = lane == 3 ? rs[3] : v;
    v = lane == 4 ? rs[4] : v;
    v = lane == 5 ? rs[5] : v;
    v = lane == 6 ? rs[6] : v;
    v = lane == 7 ? rs[7] : v;
    st_cv(vals + r0 + lane, v);
  }
  asm volatile("s_waitcnt vmcnt(0)" ::: "memory");  // whole wave: stores ack'd
}

// grid 256 blocks x 512 thr: batch = bid&15, 16 blocks/batch (1 block/CU; with
// round-robin XCD dispatch all 16 blocks of a batch share one XCD). Each wave
// owns 8 rows of A2 and 8 rows of A2T pinned in VGPRs (asm loads, 128 VGPRs).
__global__ __launch_bounds__(512, 2) void sinkhorn_kernel(
    const _Float16* __restrict__ A2, const _Float16* __restrict__ A2T,
    float* __restrict__ Fval, float* __restrict__ Gval,
    unsigned* __restrict__ Fflag, unsigned* __restrict__ Gflag,
    float* __restrict__ rOut, float* __restrict__ cOut,
    float* __restrict__ LrowOut) {
  __shared__ float ldsG[NN + NN / 8];
  __shared__ float ldsF[NN + NN / 8];
  const int batch = blockIdx.x & 15;
  const int sub = blockIdx.x >> 4;               // 0..15
  const int t = threadIdx.x;
  const int lane = t & 63;
  const int wave = t >> 6;                       // 0..7
  const int r0 = sub * 64 + wave * 8;            // 8 rows per wave
  const int j0 = lane * 8;
  const _Float16* Pa = A2 + (size_t)batch * NN * NN;
  const _Float16* Pt = A2T + (size_t)batch * NN * NN;
  float* Fvb = Fval + (size_t)batch * NN;
  float* Gvb = Gval + (size_t)batch * NN;
  unsigned* FflagB = Fflag + batch * 16;         // one 64B line per batch
  unsigned* GflagB = Gflag + batch * 16;

  h8 ra[8][2], rt[8][2];
#pragma unroll
  for (int r = 0; r < 8; ++r) {
    const _Float16* rowA = Pa + (size_t)(r0 + r) * NN + j0;
    const _Float16* rowT = Pt + (size_t)(r0 + r) * NN + j0;
    ra[r][0] = lda16(rowA);
    ra[r][1] = lda16(rowA + 512);
    rt[r][0] = lda16(rowT);
    rt[r][1] = lda16(rowT + 512);
  }

  for (int it = 0; it < 50; ++it) {
    // ---- f-phase: needs g at epoch 2it (it=0: memset zeros, flags=0 pass) ----
    if (wave == 0) waitFlags(GflagB, (unsigned)(2 * it), lane);
    __syncthreads();
    stageVals(ldsG, Gvb, t);
    __syncthreads();
    {
      float gv[16];
      ldsVec16p(ldsG, j0, gv);
      float rs[8];
#pragma unroll
      for (int r = 0; r < 8; ++r) rs[r] = lseRow(ra[r], gv);
      storeRows(Fvb, r0, rs, lane);
    }
    __syncthreads();
    if (t == 0) stu_cv(FflagB + sub, (unsigned)(2 * it + 1));
    // ---- g-phase: needs f at epoch 2it+1 ----
    if (wave == 0) waitFlags(FflagB, (unsigned)(2 * it + 1), lane);
    __syncthreads();
    stageVals(ldsF, Fvb, t);
    __syncthreads();
    {
      float fv[16];
      ldsVec16p(ldsF, j0, fv);
      float rs[8];
#pragma unroll
      for (int r = 0; r < 8; ++r) rs[r] = lseRow(rt[r], fv);
      storeRows(Gvb, r0, rs, lane);
    }
    __syncthreads();
    if (t == 0) stu_cv(GflagB + sub, (unsigned)(2 * it + 2));
  }
  // final g (epoch 100) -> ldsG ; ldsF already holds final f (epoch 99)
  if (wave == 0) waitFlags(GflagB, 100u, lane);
  __syncthreads();
  stageVals(ldsG, Gvb, t);
  __syncthreads();

  // Epilogue: r_i = sum_j T, c_j = sum_i T, Lrow_i = sum_j T*C_content
  float fv[16], gv[16];
  ldsVec16p(ldsF, j0, fv);
  ldsVec16p(ldsG, j0, gv);
#pragma unroll
  for (int r = 0; r < 8; ++r) {
    int i = r0 + r;
    float fi = ldsF[PIDX(i)];
    float gi = ldsG[PIDX(i)];
    float fr = (float)i;
    float sr = 0.f, sl = 0.f, sc = 0.f;
#pragma unroll
    for (int k = 0; k < 8; ++k) {
      float a2a = (float)ra[r][0][k];
      float a2b = (float)ra[r][1][k];
      float Ta = EXP2F(a2a + fi + gv[k]);
      float Tb = EXP2F(a2b + fi + gv[8 + k]);
      sr += Ta + Tb;
      float ca = a2a + CPOS2 * fabsf(fr - (float)(j0 + k));
      float cb = a2b + CPOS2 * fabsf(fr - (float)(512 + j0 + k));
      sl = fmaf(Ta, ca, sl);
      sl = fmaf(Tb, cb, sl);
      sc += EXP2F((float)rt[r][0][k] + gi + fv[k]);
      sc += EXP2F((float)rt[r][1][k] + gi + fv[8 + k]);
    }
    sr = waveReduceSum(sr);
    sl = waveReduceSum(sl);
    sc = waveReduceSum(sc);
    if (lane == 0) {
      rOut[batch * NN + i] = sr;
      cOut[batch * NN + i] = sc;
      LrowOut[batch * NN + i] = -C1 * sl;
    }
  }
}

// ---------------- K6: num = T @ Emb ; accumulate sum((Ref - num/denom)^2) ----------
__global__ __launch_bounds__(512) void bary_kernel(
    const _Float16* __restrict__ P, const float* __restrict__ rowv,
    const float* __restrict__ colv, const float* __restrict__ denom,
    const float* __restrict__ Emb, const float* __restrict__ Ref,
    float* __restrict__ baryAcc) {
  const int b = blockIdx.y;
  const int I0 = blockIdx.x * 64;
  const _Float16* Pb = P + (size_t)b * NN * NN;
  const float* rv = rowv + b * NN;
  const float* cvv = colv + b * NN;
  const float* dn = denom + b * NN;
  const float* Eb = Emb + (size_t)b * NN * DD;
  const float* Rb = Ref + (size_t)b * NN * DD;
  __shared__ float Tl[64 * 64];
  __shared__ float red[8];
  const int t = threadIdx.x;
  const int rg = t >> 8, d = t & 255;
  float acc[32];
#pragma unroll
  for (int k = 0; k < 32; ++k) acc[k] = 0.f;
  for (int ch = 0; ch < 16; ++ch) {
    __syncthreads();
    {
      int jj = t & 63;
      int jabs = ch * 64 + jj;
      float gvv = cvv[jabs];
      int ii0 = (t >> 6) * 8;
#pragma unroll
      for (int k = 0; k < 8; ++k) {
        int ii = ii0 + k;
        int iabs = I0 + ii;
        float a2f = (float)Pb[(size_t)iabs * NN + jabs];
        Tl[ii * 64 + jj] = EXP2F(a2f + rv[iabs] + gvv);
      }
    }
    __syncthreads();
    const float* Yc = Eb + (size_t)(ch * 64) * DD + d;
    for (int jg = 0; jg < 16; ++jg) {
      float y0 = Yc[(size_t)(jg * 4 + 0) * DD];
      float y1 = Yc[(size_t)(jg * 4 + 1) * DD];
      float y2 = Yc[(size_t)(jg * 4 + 2) * DD];
      float y3 = Yc[(size_t)(jg * 4 + 3) * DD];
#pragma unroll
      for (int ii = 0; ii < 32; ++ii) {
        const float4 tv = *(const float4*)&Tl[(rg * 32 + ii) * 64 + jg * 4];
        acc[ii] = fmaf(tv.x, y0, acc[ii]);
        acc[ii] = fmaf(tv.y, y1, acc[ii]);
        acc[ii] = fmaf(tv.z, y2, acc[ii]);
        acc[ii] = fmaf(tv.w, y3, acc[ii]);
      }
    }
  }
  float vs = 0.f;
#pragma unroll
  for (int ii = 0; ii < 32; ++ii) {
    int iabs = I0 + rg * 32 + ii;
    float val = Rb[(size_t)iabs * DD + d] - acc[ii] / (dn[iabs] + 1e-8f);
    vs = fmaf(val, val, vs);
  }
  vs = waveReduceSum(vs);
  int lane = t & 63, wave = t >> 6;
  if (lane == 0) red[wave] = vs;
  __syncthreads();
  if (t == 0) {
    float tot = 0.f;
    for (int w = 0; w < 8; ++w) tot += red[w];
    atomicAdd(baryAcc + b, tot);
  }
}

// ---------------- K7: partial global sums X*r, Y*c ----------------
__global__ __launch_bounds__(256) void xg_kernel(
    const float* __restrict__ X, const float* __restrict__ Y,
    const float* __restrict__ r, const float* __restrict__ c,
    float* __restrict__ xgp, float* __restrict__ ygp) {
  const int b = blockIdx.y, seg = blockIdx.x, d = threadIdx.x;
  float ax = 0.f, ay = 0.f;
  for (int ii = 0; ii < 256; ++ii) {
    int i = seg * 256 + ii;
    float rvv = r[b * NN + i];
    float cvv = c[b * NN + i];
    ax = fmaf(X[((size_t)b * NN + i) * DD + d], rvv, ax);
    ay = fmaf(Y[((size_t)b * NN + i) * DD + d], cvv, ay);
  }
  xgp[(size_t)(b * 4 + seg) * DD + d] = ax;
  ygp[(size_t)(b * 4 + seg) * DD + d] = ay;
}

// ---------------- K8: per-batch finalize ----------------
__global__ __launch_bounds__(256) void finalize_batch(
    const float* __restrict__ r, const float* __restrict__ c,
    const float* __restrict__ Lrow, const float* __restrict__ xgp,
    const float* __restrict__ ygp, const float* __restrict__ baryA,
    const float* __restrict__ baryB, float* __restrict__ lossArr) {
  const int b = blockIdx.x;
  const int t = threadIdx.x;
  __shared__ float sd[256];
  auto bsum = [&](float v) -> float {
    sd[t] = v; __syncthreads();
    for (int o = 128; o; o >>= 1) { if (t < o) sd[t] += sd[t + o]; __syncthreads(); }
    float res = sd[0]; __syncthreads();
    return res;
  };
  float vr = 0.f, vc = 0.f, vl = 0.f;
  for (int k = 0; k < 4; ++k) {
    int i = t + 256 * k;
    vr += r[b * NN + i];
    vc += c[b * NN + i];
    vl += Lrow[b * NN + i];
  }
  float sumR = bsum(vr);
  float sumC = bsum(vc);
  float Lmain = bsum(vl);
  float xg = (xgp[(size_t)(b * 4 + 0) * DD + t] + xgp[(size_t)(b * 4 + 1) * DD + t] +
              xgp[(size_t)(b * 4 + 2) * DD + t] + xgp[(size_t)(b * 4 + 3) * DD + t]) /
             (sumR + 1e-8f);
  float yg = (ygp[(size_t)(b * 4 + 0) * DD + t] + ygp[(size_t)(b * 4 + 1) * DD + t] +
              ygp[(size_t)(b * 4 + 2) * DD + t] + ygp[(size_t)(b * 4 + 3) * DD + t]) /
             (sumC + 1e-8f);
  float nx = bsum(xg * xg);
  float ny = bsum(yg * yg);
  float dt = bsum(xg * yg);
  if (t == 0) {
    float mx = fmaxf(sqrtf(nx), 1e-12f);
    float my = fmaxf(sqrtf(ny), 1e-12f);
    float cosv = dt / (mx * my);
    float lb = (baryA[b] + baryB[b]) * (1.0f / ((float)NN * (float)DD));
    lossArr[b] = Lmain + 0.5f * lb + 0.2f * (1.0f - cosv);
  }
}

__global__ void final_mean(const float* __restrict__ lossArr, float* __restrict__ out) {
  int t = threadIdx.x;
  float v = (t < BB) ? lossArr[t] : 0.f;
  v = waveReduceSum(v);
  if (t == 0) out[0] = v * (1.0f / BB);
}

// ---------------- launch ----------------
extern "C" void kernel_launch(void* const* d_in, const int* in_sizes, int n_in,
                              void* d_out, int out_size, void* d_ws, size_t ws_size,
                              hipStream_t stream) {
  const float* X = (const float*)d_in[0];
  const float* Y = (const float*)d_in[1];
  float* out = (float*)d_out;
  char* ws = (char*)d_ws;
  size_t off = 0;
  auto take = [&](size_t bytes) -> char* {
    char* p = ws + off;
    off = (off + bytes + 255) & ~(size_t)255;
    return p;
  };
  _Float16* Xh = (_Float16*)take((size_t)BB * NN * DD * 2);
  _Float16* Yh = (_Float16*)take((size_t)BB * NN * DD * 2);
  _Float16* A2 = (_Float16*)take((size_t)BB * NN * NN * 2);
  _Float16* A2T = (_Float16*)take((size_t)BB * NN * NN * 2);
  size_t zstart = off;
  float* Fval = (float*)take((size_t)BB * NN * 4);
  float* Gval = (float*)take((size_t)BB * NN * 4);
  unsigned* Fflag = (unsigned*)take(BB * 16 * 4);
  unsigned* Gflag = (unsigned*)take(BB * 16 * 4);
  float* baryA = (float*)take(64);
  float* baryB = (float*)take(64);
  size_t zlen = off - zstart;
  float* r = (float*)take((size_t)BB * NN * 4);
  float* c = (float*)take((size_t)BB * NN * 4);
  float* Lrow = (float*)take((size_t)BB * NN * 4);
  float* xgp = (float*)take((size_t)BB * 4 * DD * 4);
  float* ygp = (float*)take((size_t)BB * 4 * DD * 4);
  float* lossArr = (float*)take(64);
  (void)in_sizes; (void)n_in; (void)out_size; (void)ws_size;

  hipMemsetAsync(ws + zstart, 0, zlen, stream);

  normalize_kernel<<<dim3(2 * BB * NN / 4), dim3(256), 0, stream>>>(X, Y, Xh, Yh);
  gemm_a2_kernel<<<dim3(NN / 128, NN / 128, BB), dim3(256), 0, stream>>>(Xh, Yh, A2);
  gemm_a2_kernel<<<dim3(NN / 128, NN / 128, BB), dim3(256), 0, stream>>>(Yh, Xh, A2T);
  sinkhorn_kernel<<<dim3(256), dim3(512), 0, stream>>>(A2, A2T, Fval, Gval, Fflag,
                                                       Gflag, r, c, Lrow);
  bary_kernel<<<dim3(NN / 64, BB), dim3(512), 0, stream>>>(A2, Fval, Gval, r, Y, X,
                                                           baryA);
  bary_kernel<<<dim3(NN / 64, BB), dim3(512), 0, stream>>>(A2T, Gval, Fval, c, X, Y,
                                                           baryB);
  xg_kernel<<<dim3(4, BB), dim3(256), 0, stream>>>(X, Y, r, c, xgp, ygp);
  finalize_batch<<<dim3(BB), dim3(256), 0, stream>>>(r, c, Lrow, xgp, ygp, baryA, baryB,
                                                     lossArr);
  final_mean<<<dim3(1), dim3(64), 0, stream>>>(lossArr, out);
}

// Round 8
// 1608.642 us; speedup vs baseline: 1.5841x; 1.5841x over previous
//
#include <hip/hip_runtime.h>
#include <hip/hip_fp16.h>

#define BB 16
#define NN 1024
#define DD 256

typedef _Float16 h8 __attribute__((ext_vector_type(8)));
typedef _Float16 hv4 __attribute__((ext_vector_type(4)));
typedef float f32x4 __attribute__((ext_vector_type(4)));

#if __has_builtin(__builtin_amdgcn_exp2f)
#define EXP2F(x) __builtin_amdgcn_exp2f(x)
#else
#define EXP2F(x) exp2f(x)
#endif
#if __has_builtin(__builtin_amdgcn_logf)
#define LOG2F(x) __builtin_amdgcn_logf(x)
#else
#define LOG2F(x) log2f(x)
#endif

// log2-domain: A2s = -100*log2e*relu(1-S) - CPOS2*|i-j|   (pos prior folded in, fp16)
constexpr float K_A2  = -144.26950408889634f;                 // -100*log2(e)
constexpr float CPOS2 = (float)(0.2 * 1.4426950408889634 / 1023.0);
constexpr float C1    = 0.06931471805599453f;                 // ln2/10 : C_content = -C1*A2content
constexpr float BASE2 = -10.0f;                               // log2(1/1024 + 1e-12)

// padded LDS index: stride-9 kills the 16-way bank conflicts of stride-8
#define PIDX(i) ((i) + ((i) >> 3))

__device__ __forceinline__ float waveReduceSum(float v) {
#pragma unroll
  for (int o = 32; o; o >>= 1) v += __shfl_xor(v, o);
  return v;
}

__device__ __forceinline__ void ldsVec16p(const float* lds, int j0, float (&out)[16]) {
#pragma unroll
  for (int k = 0; k < 8; ++k) {
    out[k] = lds[PIDX(j0 + k)];
    out[8 + k] = lds[PIDX(512 + j0 + k)];
  }
}

__device__ __forceinline__ float lseRow(const h8 (&rw)[2], const float (&gv)[16]) {
  float x[16];
#pragma unroll
  for (int k = 0; k < 8; ++k) {
    x[k]     = (float)rw[0][k] + gv[k];
    x[8 + k] = (float)rw[1][k] + gv[8 + k];
  }
  float m = x[0];
#pragma unroll
  for (int k = 1; k < 16; ++k) m = fmaxf(m, x[k]);
#pragma unroll
  for (int o = 32; o; o >>= 1) m = fmaxf(m, __shfl_xor(m, o));
  float s = 0.f;
#pragma unroll
  for (int k = 0; k < 16; ++k) s += EXP2F(x[k] - m);
  s = waveReduceSum(s);
  return BASE2 - (m + LOG2F(s));
}

// ---------------- K1: normalize rows of X and Y -> fp16 ----------------
__global__ __launch_bounds__(256) void normalize_kernel(
    const float* __restrict__ X, const float* __restrict__ Y,
    _Float16* __restrict__ Xh, _Float16* __restrict__ Yh) {
  int wave = threadIdx.x >> 6;
  int lane = threadIdx.x & 63;
  int row = blockIdx.x * 4 + wave;           // 0 .. 2*BB*NN-1
  const float* src;
  _Float16* dst;
  if (row < BB * NN) { src = X + (size_t)row * DD; dst = Xh + (size_t)row * DD; }
  else { int r2 = row - BB * NN; src = Y + (size_t)r2 * DD; dst = Yh + (size_t)r2 * DD; }
  float4 v = *(const float4*)(src + lane * 4);
  float ss = v.x * v.x + v.y * v.y + v.z * v.z + v.w * v.w;
  ss = waveReduceSum(ss);
  float sc = 1.0f / fmaxf(sqrtf(ss), 1e-12f);
  hv4 hv;
  hv[0] = (_Float16)(v.x * sc); hv[1] = (_Float16)(v.y * sc);
  hv[2] = (_Float16)(v.z * sc); hv[3] = (_Float16)(v.w * sc);
  *(hv4*)(dst + lane * 4) = hv;
}

// ---------------- K2: S = Ah . Bh^T per batch, write A2s (content+pos, fp16) ----
__global__ __launch_bounds__(256) void gemm_a2_kernel(
    const _Float16* __restrict__ Ah, const _Float16* __restrict__ Bh,
    _Float16* __restrict__ Out) {
  const int b = blockIdx.z;
  const int I0 = blockIdx.y * 128;
  const int J0 = blockIdx.x * 128;
  const int lane = threadIdx.x & 63;
  const int wave = threadIdx.x >> 6;
  const int m = lane & 15, quad = lane >> 4;
  const _Float16* Abase = Ah + ((size_t)b * NN + I0 + wave * 32) * DD;
  const _Float16* Bbase = Bh + ((size_t)b * NN + J0) * DD;
  f32x4 acc[2][8] = {};
  for (int k0 = 0; k0 < DD; k0 += 32) {
    int koff = k0 + quad * 8;
    h8 a0 = *(const h8*)(Abase + (size_t)m * DD + koff);
    h8 a1 = *(const h8*)(Abase + (size_t)(m + 16) * DD + koff);
#pragma unroll
    for (int t = 0; t < 8; ++t) {
      h8 bf = *(const h8*)(Bbase + (size_t)(t * 16 + m) * DD + koff);
      acc[0][t] = __builtin_amdgcn_mfma_f32_16x16x32_f16(a0, bf, acc[0][t], 0, 0, 0);
      acc[1][t] = __builtin_amdgcn_mfma_f32_16x16x32_f16(a1, bf, acc[1][t], 0, 0, 0);
    }
  }
  _Float16* Ob = Out + ((size_t)b * NN + I0 + wave * 32) * NN + J0;
#pragma unroll
  for (int a = 0; a < 2; ++a)
#pragma unroll
    for (int t = 0; t < 8; ++t)
#pragma unroll
      for (int r = 0; r < 4; ++r) {
        int row = a * 16 + quad * 4 + r;
        int col = t * 16 + m;
        float s = acc[a][t][r];
        float ri = (float)(I0 + wave * 32 + row);
        float ci = (float)(J0 + col);
        Ob[(size_t)row * NN + col] =
            (_Float16)(K_A2 * fmaxf(1.0f - s, 0.0f) - CPOS2 * fabsf(ri - ci));
      }
}

// ---------------- K3: one sinkhorn half-iteration (one dispatch per phase) -------
// vout[b][i] = BASE2 - lse2_j( P[b][i][j] + vin[b][j] )
// All loads plain/cached; device-wide sync + cache coherence comes free from the
// dispatch boundary (rounds 3-7 showed in-kernel cross-XCD exchange costs
// ~16 us/phase in uncached line-amplified traffic - the dispatch boundary's bulk
// L2 maintenance is far cheaper).
// grid (64, BB) x 256 thr: block stages vin (4 KB) to LDS, computes 16 rows.
__global__ __launch_bounds__(256) void sink_half_kernel(
    const _Float16* __restrict__ P, const float* __restrict__ vin,
    float* __restrict__ vout) {
  __shared__ float lv[NN + NN / 8];
  const int b = blockIdx.y;
  const int t = threadIdx.x, lane = t & 63, wave = t >> 6;
  float4 v = *(const float4*)(vin + b * NN + 4 * t);
  lv[PIDX(4 * t + 0)] = v.x;
  lv[PIDX(4 * t + 1)] = v.y;
  lv[PIDX(4 * t + 2)] = v.z;
  lv[PIDX(4 * t + 3)] = v.w;
  __syncthreads();
  const int j0 = lane * 8;
  float gv[16];
  ldsVec16p(lv, j0, gv);
  const _Float16* Pb = P + (size_t)b * NN * NN;
  const int row0 = blockIdx.x * 16 + wave * 4;
  h8 q[4][2];
#pragma unroll
  for (int r = 0; r < 4; ++r) {
    q[r][0] = *(const h8*)(Pb + (size_t)(row0 + r) * NN + j0);
    q[r][1] = *(const h8*)(Pb + (size_t)(row0 + r) * NN + 512 + j0);
  }
#pragma unroll
  for (int r = 0; r < 4; ++r) {
    float res = lseRow(q[r], gv);
    if (lane == 0) vout[b * NN + row0 + r] = res;
  }
}

// ---------------- K4: marginals (+ L_main on the row pass) ----------------
// outS[i] = sum_j T ; outL[i] = -C1 * sum_j T * (a2s + CPOS2*|i-j|)
__global__ __launch_bounds__(512) void marginals_kernel(
    const _Float16* __restrict__ P, const float* __restrict__ rowv,
    const float* __restrict__ colv, float* __restrict__ outS,
    float* __restrict__ outL) {
  __shared__ float lv[NN + NN / 8];
  const int b = blockIdx.y, sub = blockIdx.x;  // sub 0..7
  const int t = threadIdx.x, lane = t & 63, wave = t >> 6;
  float2 v = *(const float2*)(colv + b * NN + 2 * t);
  lv[PIDX(2 * t + 0)] = v.x;
  lv[PIDX(2 * t + 1)] = v.y;
  __syncthreads();
  const int j0 = lane * 8;
  float gv[16];
  ldsVec16p(lv, j0, gv);
  const _Float16* Pb = P + (size_t)b * NN * NN;
  const int wg = sub * 8 + wave;               // 0..63
  for (int s = 0; s < 16; ++s) {
    int i = wg + s * 64;
    float fi = rowv[b * NN + i];
    const _Float16* row = Pb + (size_t)i * NN;
    h8 qa = *(const h8*)(row + j0);
    h8 qb = *(const h8*)(row + 512 + j0);
    float fr = (float)i;
    float sr = 0.f, sl = 0.f;
#pragma unroll
    for (int k = 0; k < 8; ++k) {
      float a2a = (float)qa[k];
      float a2b = (float)qb[k];
      float Ta = EXP2F(a2a + fi + gv[k]);
      float Tb = EXP2F(a2b + fi + gv[8 + k]);
      sr += Ta + Tb;
      float ca = a2a + CPOS2 * fabsf(fr - (float)(j0 + k));
      float cb = a2b + CPOS2 * fabsf(fr - (float)(512 + j0 + k));
      sl = fmaf(Ta, ca, sl);
      sl = fmaf(Tb, cb, sl);
    }
    sr = waveReduceSum(sr);
    sl = waveReduceSum(sl);
    if (lane == 0) { outS[b * NN + i] = sr; outL[b * NN + i] = -C1 * sl; }
  }
}

// ---------------- K6: num = T @ Emb ; accumulate sum((Ref - num/denom)^2) ----------
__global__ __launch_bounds__(512) void bary_kernel(
    const _Float16* __restrict__ P, const float* __restrict__ rowv,
    const float* __restrict__ colv, const float* __restrict__ denom,
    const float* __restrict__ Emb, const float* __restrict__ Ref,
    float* __restrict__ baryAcc) {
  const int b = blockIdx.y;
  const int I0 = blockIdx.x * 64;
  const _Float16* Pb = P + (size_t)b * NN * NN;
  const float* rv = rowv + b * NN;
  const float* cvv = colv + b * NN;
  const float* dn = denom + b * NN;
  const float* Eb = Emb + (size_t)b * NN * DD;
  const float* Rb = Ref + (size_t)b * NN * DD;
  __shared__ float Tl[64 * 64];
  __shared__ float red[8];
  const int t = threadIdx.x;
  const int rg = t >> 8, d = t & 255;
  float acc[32];
#pragma unroll
  for (int k = 0; k < 32; ++k) acc[k] = 0.f;
  for (int ch = 0; ch < 16; ++ch) {
    __syncthreads();
    {
      int jj = t & 63;
      int jabs = ch * 64 + jj;
      float gvv = cvv[jabs];
      int ii0 = (t >> 6) * 8;
#pragma unroll
      for (int k = 0; k < 8; ++k) {
        int ii = ii0 + k;
        int iabs = I0 + ii;
        float a2f = (float)Pb[(size_t)iabs * NN + jabs];
        Tl[ii * 64 + jj] = EXP2F(a2f + rv[iabs] + gvv);
      }
    }
    __syncthreads();
    const float* Yc = Eb + (size_t)(ch * 64) * DD + d;
    for (int jg = 0; jg < 16; ++jg) {
      float y0 = Yc[(size_t)(jg * 4 + 0) * DD];
      float y1 = Yc[(size_t)(jg * 4 + 1) * DD];
      float y2 = Yc[(size_t)(jg * 4 + 2) * DD];
      float y3 = Yc[(size_t)(jg * 4 + 3) * DD];
#pragma unroll
      for (int ii = 0; ii < 32; ++ii) {
        const float4 tv = *(const float4*)&Tl[(rg * 32 + ii) * 64 + jg * 4];
        acc[ii] = fmaf(tv.x, y0, acc[ii]);
        acc[ii] = fmaf(tv.y, y1, acc[ii]);
        acc[ii] = fmaf(tv.z, y2, acc[ii]);
        acc[ii] = fmaf(tv.w, y3, acc[ii]);
      }
    }
  }
  float vs = 0.f;
#pragma unroll
  for (int ii = 0; ii < 32; ++ii) {
    int iabs = I0 + rg * 32 + ii;
    float val = Rb[(size_t)iabs * DD + d] - acc[ii] / (dn[iabs] + 1e-8f);
    vs = fmaf(val, val, vs);
  }
  vs = waveReduceSum(vs);
  int lane = t & 63, wave = t >> 6;
  if (lane == 0) red[wave] = vs;
  __syncthreads();
  if (t == 0) {
    float tot = 0.f;
    for (int w = 0; w < 8; ++w) tot += red[w];
    atomicAdd(baryAcc + b, tot);
  }
}

// ---------------- K7: partial global sums X*r, Y*c ----------------
__global__ __launch_bounds__(256) void xg_kernel(
    const float* __restrict__ X, const float* __restrict__ Y,
    const float* __restrict__ r, const float* __restrict__ c,
    float* __restrict__ xgp, float* __restrict__ ygp) {
  const int b = blockIdx.y, seg = blockIdx.x, d = threadIdx.x;
  float ax = 0.f, ay = 0.f;
  for (int ii = 0; ii < 256; ++ii) {
    int i = seg * 256 + ii;
    float rvv = r[b * NN + i];
    float cvv = c[b * NN + i];
    ax = fmaf(X[((size_t)b * NN + i) * DD + d], rvv, ax);
    ay = fmaf(Y[((size_t)b * NN + i) * DD + d], cvv, ay);
  }
  xgp[(size_t)(b * 4 + seg) * DD + d] = ax;
  ygp[(size_t)(b * 4 + seg) * DD + d] = ay;
}

// ---------------- K8: per-batch finalize ----------------
__global__ __launch_bounds__(256) void finalize_batch(
    const float* __restrict__ r, const float* __restrict__ c,
    const float* __restrict__ Lrow, const float* __restrict__ xgp,
    const float* __restrict__ ygp, const float* __restrict__ baryA,
    const float* __restrict__ baryB, float* __restrict__ lossArr) {
  const int b = blockIdx.x;
  const int t = threadIdx.x;
  __shared__ float sd[256];
  auto bsum = [&](float v) -> float {
    sd[t] = v; __syncthreads();
    for (int o = 128; o; o >>= 1) { if (t < o) sd[t] += sd[t + o]; __syncthreads(); }
    float res = sd[0]; __syncthreads();
    return res;
  };
  float vr = 0.f, vc = 0.f, vl = 0.f;
  for (int k = 0; k < 4; ++k) {
    int i = t + 256 * k;
    vr += r[b * NN + i];
    vc += c[b * NN + i];
    vl += Lrow[b * NN + i];
  }
  float sumR = bsum(vr);
  float sumC = bsum(vc);
  float Lmain = bsum(vl);
  float xg = (xgp[(size_t)(b * 4 + 0) * DD + t] + xgp[(size_t)(b * 4 + 1) * DD + t] +
              xgp[(size_t)(b * 4 + 2) * DD + t] + xgp[(size_t)(b * 4 + 3) * DD + t]) /
             (sumR + 1e-8f);
  float yg = (ygp[(size_t)(b * 4 + 0) * DD + t] + ygp[(size_t)(b * 4 + 1) * DD + t] +
              ygp[(size_t)(b * 4 + 2) * DD + t] + ygp[(size_t)(b * 4 + 3) * DD + t]) /
             (sumC + 1e-8f);
  float nx = bsum(xg * xg);
  float ny = bsum(yg * yg);
  float dt = bsum(xg * yg);
  if (t == 0) {
    float mx = fmaxf(sqrtf(nx), 1e-12f);
    float my = fmaxf(sqrtf(ny), 1e-12f);
    float cosv = dt / (mx * my);
    float lb = (baryA[b] + baryB[b]) * (1.0f / ((float)NN * (float)DD));
    lossArr[b] = Lmain + 0.5f * lb + 0.2f * (1.0f - cosv);
  }
}

__global__ void final_mean(const float* __restrict__ lossArr, float* __restrict__ out) {
  int t = threadIdx.x;
  float v = (t < BB) ? lossArr[t] : 0.f;
  v = waveReduceSum(v);
  if (t == 0) out[0] = v * (1.0f / BB);
}

// ---------------- launch ----------------
extern "C" void kernel_launch(void* const* d_in, const int* in_sizes, int n_in,
                              void* d_out, int out_size, void* d_ws, size_t ws_size,
                              hipStream_t stream) {
  const float* X = (const float*)d_in[0];
  const float* Y = (const float*)d_in[1];
  float* out = (float*)d_out;
  char* ws = (char*)d_ws;
  size_t off = 0;
  auto take = [&](size_t bytes) -> char* {
    char* p = ws + off;
    off = (off + bytes + 255) & ~(size_t)255;
    return p;
  };
  _Float16* Xh = (_Float16*)take((size_t)BB * NN * DD * 2);
  _Float16* Yh = (_Float16*)take((size_t)BB * NN * DD * 2);
  _Float16* A2 = (_Float16*)take((size_t)BB * NN * NN * 2);
  _Float16* A2T = (_Float16*)take((size_t)BB * NN * NN * 2);
  size_t zstart = off;
  float* G = (float*)take((size_t)BB * NN * 4);
  float* baryA = (float*)take(64);
  float* baryB = (float*)take(64);
  size_t zlen = off - zstart;
  float* F = (float*)take((size_t)BB * NN * 4);
  float* r = (float*)take((size_t)BB * NN * 4);
  float* c = (float*)take((size_t)BB * NN * 4);
  float* Lrow = (float*)take((size_t)BB * NN * 4);
  float* Lcol = (float*)take((size_t)BB * NN * 4);   // discarded
  float* xgp = (float*)take((size_t)BB * 4 * DD * 4);
  float* ygp = (float*)take((size_t)BB * 4 * DD * 4);
  float* lossArr = (float*)take(64);
  (void)in_sizes; (void)n_in; (void)out_size; (void)ws_size;

  hipMemsetAsync(ws + zstart, 0, zlen, stream);

  normalize_kernel<<<dim3(2 * BB * NN / 4), dim3(256), 0, stream>>>(X, Y, Xh, Yh);
  gemm_a2_kernel<<<dim3(NN / 128, NN / 128, BB), dim3(256), 0, stream>>>(Xh, Yh, A2);
  gemm_a2_kernel<<<dim3(NN / 128, NN / 128, BB), dim3(256), 0, stream>>>(Yh, Xh, A2T);
  for (int it = 0; it < 50; ++it) {
    sink_half_kernel<<<dim3(64, BB), dim3(256), 0, stream>>>(A2, G, F);
    sink_half_kernel<<<dim3(64, BB), dim3(256), 0, stream>>>(A2T, F, G);
  }
  marginals_kernel<<<dim3(8, BB), dim3(512), 0, stream>>>(A2, F, G, r, Lrow);
  marginals_kernel<<<dim3(8, BB), dim3(512), 0, stream>>>(A2T, G, F, c, Lcol);
  bary_kernel<<<dim3(NN / 64, BB), dim3(512), 0, stream>>>(A2, F, G, r, Y, X, baryA);
  bary_kernel<<<dim3(NN / 64, BB), dim3(512), 0, stream>>>(A2T, G, F, c, X, Y, baryB);
  xg_kernel<<<dim3(4, BB), dim3(256), 0, stream>>>(X, Y, r, c, xgp, ygp);
  finalize_batch<<<dim3(BB), dim3(256), 0, stream>>>(r, c, Lrow, xgp, ygp, baryA, baryB,
                                                     lossArr);
  final_mean<<<dim3(1), dim3(64), 0, stream>>>(lossArr, out);
}

// Round 9
// 1240.659 us; speedup vs baseline: 2.0539x; 1.2966x over previous
//
#include <hip/hip_runtime.h>
#include <hip/hip_fp16.h>

#define BB 16
#define NN 1024
#define DD 256

typedef _Float16 h8 __attribute__((ext_vector_type(8)));
typedef _Float16 hv4 __attribute__((ext_vector_type(4)));
typedef float f32x4 __attribute__((ext_vector_type(4)));

#if __has_builtin(__builtin_amdgcn_exp2f)
#define EXP2F(x) __builtin_amdgcn_exp2f(x)
#else
#define EXP2F(x) exp2f(x)
#endif
#if __has_builtin(__builtin_amdgcn_logf)
#define LOG2F(x) __builtin_amdgcn_logf(x)
#else
#define LOG2F(x) log2f(x)
#endif

// log2-domain: A2s = -100*log2e*relu(1-S) - CPOS2*|i-j|   (pos prior folded in, fp16)
constexpr float K_A2  = -144.26950408889634f;                 // -100*log2(e)
constexpr float CPOS2 = (float)(0.2 * 1.4426950408889634 / 1023.0);
constexpr float C1    = 0.06931471805599453f;                 // ln2/10 : C_content = -C1*A2content
constexpr float BASE2 = -10.0f;                               // log2(1/1024 + 1e-12)

// padded LDS index: stride-9 kills the 16-way bank conflicts of stride-8
#define PIDX(i) ((i) + ((i) >> 3))

__device__ __forceinline__ float waveReduceSum(float v) {
#pragma unroll
  for (int o = 32; o; o >>= 1) v += __shfl_xor(v, o);
  return v;
}

__device__ __forceinline__ void ldsVec16p(const float* lds, int j0, float (&out)[16]) {
#pragma unroll
  for (int k = 0; k < 8; ++k) {
    out[k] = lds[PIDX(j0 + k)];
    out[8 + k] = lds[PIDX(512 + j0 + k)];
  }
}

__device__ __forceinline__ float lseRow(const h8 (&rw)[2], const float (&gv)[16]) {
  float x[16];
#pragma unroll
  for (int k = 0; k < 8; ++k) {
    x[k]     = (float)rw[0][k] + gv[k];
    x[8 + k] = (float)rw[1][k] + gv[8 + k];
  }
  float m = x[0];
#pragma unroll
  for (int k = 1; k < 16; ++k) m = fmaxf(m, x[k]);
#pragma unroll
  for (int o = 32; o; o >>= 1) m = fmaxf(m, __shfl_xor(m, o));
  float s = 0.f;
#pragma unroll
  for (int k = 0; k < 16; ++k) s += EXP2F(x[k] - m);
  s = waveReduceSum(s);
  return BASE2 - (m + LOG2F(s));
}

// ---------------- K1: normalize rows of X and Y -> fp16 ----------------
__global__ __launch_bounds__(256) void normalize_kernel(
    const float* __restrict__ X, const float* __restrict__ Y,
    _Float16* __restrict__ Xh, _Float16* __restrict__ Yh) {
  int wave = threadIdx.x >> 6;
  int lane = threadIdx.x & 63;
  int row = blockIdx.x * 4 + wave;           // 0 .. 2*BB*NN-1
  const float* src;
  _Float16* dst;
  if (row < BB * NN) { src = X + (size_t)row * DD; dst = Xh + (size_t)row * DD; }
  else { int r2 = row - BB * NN; src = Y + (size_t)r2 * DD; dst = Yh + (size_t)r2 * DD; }
  float4 v = *(const float4*)(src + lane * 4);
  float ss = v.x * v.x + v.y * v.y + v.z * v.z + v.w * v.w;
  ss = waveReduceSum(ss);
  float sc = 1.0f / fmaxf(sqrtf(ss), 1e-12f);
  hv4 hv;
  hv[0] = (_Float16)(v.x * sc); hv[1] = (_Float16)(v.y * sc);
  hv[2] = (_Float16)(v.z * sc); hv[3] = (_Float16)(v.w * sc);
  *(hv4*)(dst + lane * 4) = hv;
}

// ---------------- K1b: tiled transpose X,Y -> fp16 [b][d][n] ----------------
// grid (NN/64, DD/64, 2*BB), block 256
__global__ __launch_bounds__(256) void transpose_kernel(
    const float* __restrict__ X, const float* __restrict__ Y,
    _Float16* __restrict__ XT, _Float16* __restrict__ YT) {
  __shared__ _Float16 tile[64][72];
  int zb = blockIdx.z;
  const float* E;
  _Float16* ET;
  if (zb < BB) { E = X + (size_t)zb * NN * DD; ET = XT + (size_t)zb * DD * NN; }
  else { E = Y + (size_t)(zb - BB) * NN * DD; ET = YT + (size_t)(zb - BB) * DD * NN; }
  int n0 = blockIdx.x * 64, d0 = blockIdx.y * 64;
  int t = threadIdx.x;
  int lr = t >> 2, lc = (t & 3) * 16;
#pragma unroll
  for (int k = 0; k < 16; k += 4) {
    float4 v = *(const float4*)(E + (size_t)(n0 + lr) * DD + d0 + lc + k);
    tile[lc + k + 0][lr] = (_Float16)v.x;
    tile[lc + k + 1][lr] = (_Float16)v.y;
    tile[lc + k + 2][lr] = (_Float16)v.z;
    tile[lc + k + 3][lr] = (_Float16)v.w;
  }
  __syncthreads();
#pragma unroll
  for (int k = 0; k < 16; k += 8) {
    h8 o;
#pragma unroll
    for (int j = 0; j < 8; ++j) o[j] = tile[lr][lc + k + j];
    *(h8*)(ET + (size_t)(d0 + lr) * NN + n0 + lc + k) = o;
  }
}

// ---------------- K2: S = Ah . Bh^T per batch, write A2s (content+pos, fp16) ----
__global__ __launch_bounds__(256) void gemm_a2_kernel(
    const _Float16* __restrict__ Ah, const _Float16* __restrict__ Bh,
    _Float16* __restrict__ Out) {
  const int b = blockIdx.z;
  const int I0 = blockIdx.y * 128;
  const int J0 = blockIdx.x * 128;
  const int lane = threadIdx.x & 63;
  const int wave = threadIdx.x >> 6;
  const int m = lane & 15, quad = lane >> 4;
  const _Float16* Abase = Ah + ((size_t)b * NN + I0 + wave * 32) * DD;
  const _Float16* Bbase = Bh + ((size_t)b * NN + J0) * DD;
  f32x4 acc[2][8] = {};
  for (int k0 = 0; k0 < DD; k0 += 32) {
    int koff = k0 + quad * 8;
    h8 a0 = *(const h8*)(Abase + (size_t)m * DD + koff);
    h8 a1 = *(const h8*)(Abase + (size_t)(m + 16) * DD + koff);
#pragma unroll
    for (int t = 0; t < 8; ++t) {
      h8 bf = *(const h8*)(Bbase + (size_t)(t * 16 + m) * DD + koff);
      acc[0][t] = __builtin_amdgcn_mfma_f32_16x16x32_f16(a0, bf, acc[0][t], 0, 0, 0);
      acc[1][t] = __builtin_amdgcn_mfma_f32_16x16x32_f16(a1, bf, acc[1][t], 0, 0, 0);
    }
  }
  _Float16* Ob = Out + ((size_t)b * NN + I0 + wave * 32) * NN + J0;
#pragma unroll
  for (int a = 0; a < 2; ++a)
#pragma unroll
    for (int t = 0; t < 8; ++t)
#pragma unroll
      for (int r = 0; r < 4; ++r) {
        int row = a * 16 + quad * 4 + r;
        int col = t * 16 + m;
        float s = acc[a][t][r];
        float ri = (float)(I0 + wave * 32 + row);
        float ci = (float)(J0 + col);
        Ob[(size_t)row * NN + col] =
            (_Float16)(K_A2 * fmaxf(1.0f - s, 0.0f) - CPOS2 * fabsf(ri - ci));
      }
}

// ---------------- K3: one sinkhorn half-iteration (one dispatch per phase) -------
__global__ __launch_bounds__(256) void sink_half_kernel(
    const _Float16* __restrict__ P, const float* __restrict__ vin,
    float* __restrict__ vout) {
  __shared__ float lv[NN + NN / 8];
  const int b = blockIdx.y;
  const int t = threadIdx.x, lane = t & 63, wave = t >> 6;
  float4 v = *(const float4*)(vin + b * NN + 4 * t);
  lv[PIDX(4 * t + 0)] = v.x;
  lv[PIDX(4 * t + 1)] = v.y;
  lv[PIDX(4 * t + 2)] = v.z;
  lv[PIDX(4 * t + 3)] = v.w;
  __syncthreads();
  const int j0 = lane * 8;
  float gv[16];
  ldsVec16p(lv, j0, gv);
  const _Float16* Pb = P + (size_t)b * NN * NN;
  const int row0 = blockIdx.x * 16 + wave * 4;
  h8 q[4][2];
#pragma unroll
  for (int r = 0; r < 4; ++r) {
    q[r][0] = *(const h8*)(Pb + (size_t)(row0 + r) * NN + j0);
    q[r][1] = *(const h8*)(Pb + (size_t)(row0 + r) * NN + 512 + j0);
  }
#pragma unroll
  for (int r = 0; r < 4; ++r) {
    float res = lseRow(q[r], gv);
    if (lane == 0) vout[b * NN + row0 + r] = res;
  }
}

// ---------------- K4: marginals (+ L_main on the row pass) ----------------
__global__ __launch_bounds__(512) void marginals_kernel(
    const _Float16* __restrict__ P, const float* __restrict__ rowv,
    const float* __restrict__ colv, float* __restrict__ outS,
    float* __restrict__ outL) {
  __shared__ float lv[NN + NN / 8];
  const int b = blockIdx.y, sub = blockIdx.x;  // sub 0..7
  const int t = threadIdx.x, lane = t & 63, wave = t >> 6;
  float2 v = *(const float2*)(colv + b * NN + 2 * t);
  lv[PIDX(2 * t + 0)] = v.x;
  lv[PIDX(2 * t + 1)] = v.y;
  __syncthreads();
  const int j0 = lane * 8;
  float gv[16];
  ldsVec16p(lv, j0, gv);
  const _Float16* Pb = P + (size_t)b * NN * NN;
  const int wg = sub * 8 + wave;               // 0..63
  for (int s = 0; s < 16; ++s) {
    int i = wg + s * 64;
    float fi = rowv[b * NN + i];
    const _Float16* row = Pb + (size_t)i * NN;
    h8 qa = *(const h8*)(row + j0);
    h8 qb = *(const h8*)(row + 512 + j0);
    float fr = (float)i;
    float sr = 0.f, sl = 0.f;
#pragma unroll
    for (int k = 0; k < 8; ++k) {
      float a2a = (float)qa[k];
      float a2b = (float)qb[k];
      float Ta = EXP2F(a2a + fi + gv[k]);
      float Tb = EXP2F(a2b + fi + gv[8 + k]);
      sr += Ta + Tb;
      float ca = a2a + CPOS2 * fabsf(fr - (float)(j0 + k));
      float cb = a2b + CPOS2 * fabsf(fr - (float)(512 + j0 + k));
      sl = fmaf(Ta, ca, sl);
      sl = fmaf(Tb, cb, sl);
    }
    sr = waveReduceSum(sr);
    sl = waveReduceSum(sl);
    if (lane == 0) { outS[b * NN + i] = sr; outL[b * NN + i] = -C1 * sl; }
  }
}

// ---------------- K6: MFMA bary: num = T @ Emb ; sum((Ref - num/denom)^2) --------
// T computed on the fly in A-fragment layout: Ta = exp2(a2 + f_i + g_j + 10)
// (the 2^10 scale keeps fp16 T values O(1); epilogue divides by 1024*denom).
// EmbT is raw fp16 [b][d][n] so the B-fragment is one contiguous h8 per tile.
// grid (NN/64, BB), block 256 (4 waves, wave w owns rows I0+w*16..+15).
__global__ __launch_bounds__(256) void bary_mfma_kernel(
    const _Float16* __restrict__ P, const float* __restrict__ rowv,
    const float* __restrict__ colv, const float* __restrict__ denom,
    const _Float16* __restrict__ EmbT, const float* __restrict__ Ref,
    float* __restrict__ baryAcc) {
  __shared__ float gl[NN];
  __shared__ float red[4];
  const int b = blockIdx.y;
  const int I0 = blockIdx.x * 64;
  const int t = threadIdx.x, lane = t & 63, wave = t >> 6;
  const int m = lane & 15, quad = lane >> 4;
  gl[t] = colv[b * NN + t];
  gl[t + 256] = colv[b * NN + t + 256];
  gl[t + 512] = colv[b * NN + t + 512];
  gl[t + 768] = colv[b * NN + t + 768];
  __syncthreads();
  const int row = I0 + wave * 16 + m;                 // A-frag row for this lane
  const float fi = rowv[b * NN + row] + 10.0f;        // fold 2^10 scale
  const _Float16* Pr = P + (size_t)b * NN * NN + (size_t)row * NN + quad * 8;
  const _Float16* ET = EmbT + (size_t)b * DD * NN;
  f32x4 acc[16];
#pragma unroll
  for (int i = 0; i < 16; ++i) acc[i] = (f32x4){0.f, 0.f, 0.f, 0.f};
  for (int kc = 0; kc < NN; kc += 32) {
    h8 a2v = *(const h8*)(Pr + kc);
    float4 g0 = *(const float4*)&gl[kc + quad * 8];
    float4 g1 = *(const float4*)&gl[kc + quad * 8 + 4];
    h8 af;
    af[0] = (_Float16)EXP2F((float)a2v[0] + fi + g0.x);
    af[1] = (_Float16)EXP2F((float)a2v[1] + fi + g0.y);
    af[2] = (_Float16)EXP2F((float)a2v[2] + fi + g0.z);
    af[3] = (_Float16)EXP2F((float)a2v[3] + fi + g0.w);
    af[4] = (_Float16)EXP2F((float)a2v[4] + fi + g1.x);
    af[5] = (_Float16)EXP2F((float)a2v[5] + fi + g1.y);
    af[6] = (_Float16)EXP2F((float)a2v[6] + fi + g1.z);
    af[7] = (_Float16)EXP2F((float)a2v[7] + fi + g1.w);
#pragma unroll
    for (int nt = 0; nt < 16; ++nt) {
      h8 bf = *(const h8*)(ET + (size_t)(nt * 16 + m) * NN + kc + quad * 8);
      acc[nt] = __builtin_amdgcn_mfma_f32_16x16x32_f16(af, bf, acc[nt], 0, 0, 0);
    }
  }
  // epilogue: C layout col = nt*16+m, row = quad*4 + r
  float vs = 0.f;
#pragma unroll
  for (int r4 = 0; r4 < 4; ++r4) {
    int iabs = I0 + wave * 16 + quad * 4 + r4;
    float inv = 1.0f / (1024.0f * (denom[b * NN + iabs] + 1e-8f));
    const float* Rrow = Ref + ((size_t)b * NN + iabs) * DD;
#pragma unroll
    for (int nt = 0; nt < 16; ++nt) {
      int d = nt * 16 + m;
      float val = Rrow[d] - acc[nt][r4] * inv;
      vs = fmaf(val, val, vs);
    }
  }
  vs = waveReduceSum(vs);
  if (lane == 0) red[wave] = vs;
  __syncthreads();
  if (t == 0) atomicAdd(baryAcc + b, red[0] + red[1] + red[2] + red[3]);
}

// ---------------- K7: partial global sums X*r, Y*c ----------------
__global__ __launch_bounds__(256) void xg_kernel(
    const float* __restrict__ X, const float* __restrict__ Y,
    const float* __restrict__ r, const float* __restrict__ c,
    float* __restrict__ xgp, float* __restrict__ ygp) {
  const int b = blockIdx.y, seg = blockIdx.x, d = threadIdx.x;
  float ax = 0.f, ay = 0.f;
  for (int ii = 0; ii < 256; ++ii) {
    int i = seg * 256 + ii;
    float rvv = r[b * NN + i];
    float cvv = c[b * NN + i];
    ax = fmaf(X[((size_t)b * NN + i) * DD + d], rvv, ax);
    ay = fmaf(Y[((size_t)b * NN + i) * DD + d], cvv, ay);
  }
  xgp[(size_t)(b * 4 + seg) * DD + d] = ax;
  ygp[(size_t)(b * 4 + seg) * DD + d] = ay;
}

// ---------------- K8: per-batch finalize ----------------
__global__ __launch_bounds__(256) void finalize_batch(
    const float* __restrict__ r, const float* __restrict__ c,
    const float* __restrict__ Lrow, const float* __restrict__ xgp,
    const float* __restrict__ ygp, const float* __restrict__ baryA,
    const float* __restrict__ baryB, float* __restrict__ lossArr) {
  const int b = blockIdx.x;
  const int t = threadIdx.x;
  __shared__ float sd[256];
  auto bsum = [&](float v) -> float {
    sd[t] = v; __syncthreads();
    for (int o = 128; o; o >>= 1) { if (t < o) sd[t] += sd[t + o]; __syncthreads(); }
    float res = sd[0]; __syncthreads();
    return res;
  };
  float vr = 0.f, vc = 0.f, vl = 0.f;
  for (int k = 0; k < 4; ++k) {
    int i = t + 256 * k;
    vr += r[b * NN + i];
    vc += c[b * NN + i];
    vl += Lrow[b * NN + i];
  }
  float sumR = bsum(vr);
  float sumC = bsum(vc);
  float Lmain = bsum(vl);
  float xg = (xgp[(size_t)(b * 4 + 0) * DD + t] + xgp[(size_t)(b * 4 + 1) * DD + t] +
              xgp[(size_t)(b * 4 + 2) * DD + t] + xgp[(size_t)(b * 4 + 3) * DD + t]) /
             (sumR + 1e-8f);
  float yg = (ygp[(size_t)(b * 4 + 0) * DD + t] + ygp[(size_t)(b * 4 + 1) * DD + t] +
              ygp[(size_t)(b * 4 + 2) * DD + t] + ygp[(size_t)(b * 4 + 3) * DD + t]) /
             (sumC + 1e-8f);
  float nx = bsum(xg * xg);
  float ny = bsum(yg * yg);
  float dt = bsum(xg * yg);
  if (t == 0) {
    float mx = fmaxf(sqrtf(nx), 1e-12f);
    float my = fmaxf(sqrtf(ny), 1e-12f);
    float cosv = dt / (mx * my);
    float lb = (baryA[b] + baryB[b]) * (1.0f / ((float)NN * (float)DD));
    lossArr[b] = Lmain + 0.5f * lb + 0.2f * (1.0f - cosv);
  }
}

__global__ void final_mean(const float* __restrict__ lossArr, float* __restrict__ out) {
  int t = threadIdx.x;
  float v = (t < BB) ? lossArr[t] : 0.f;
  v = waveReduceSum(v);
  if (t == 0) out[0] = v * (1.0f / BB);
}

// ---------------- launch ----------------
extern "C" void kernel_launch(void* const* d_in, const int* in_sizes, int n_in,
                              void* d_out, int out_size, void* d_ws, size_t ws_size,
                              hipStream_t stream) {
  const float* X = (const float*)d_in[0];
  const float* Y = (const float*)d_in[1];
  float* out = (float*)d_out;
  char* ws = (char*)d_ws;
  size_t off = 0;
  auto take = [&](size_t bytes) -> char* {
    char* p = ws + off;
    off = (off + bytes + 255) & ~(size_t)255;
    return p;
  };
  _Float16* Xh = (_Float16*)take((size_t)BB * NN * DD * 2);
  _Float16* Yh = (_Float16*)take((size_t)BB * NN * DD * 2);
  _Float16* XT_h = (_Float16*)take((size_t)BB * DD * NN * 2);
  _Float16* YT_h = (_Float16*)take((size_t)BB * DD * NN * 2);
  _Float16* A2 = (_Float16*)take((size_t)BB * NN * NN * 2);
  _Float16* A2T = (_Float16*)take((size_t)BB * NN * NN * 2);
  size_t zstart = off;
  float* G = (float*)take((size_t)BB * NN * 4);
  float* baryA = (float*)take(64);
  float* baryB = (float*)take(64);
  size_t zlen = off - zstart;
  float* F = (float*)take((size_t)BB * NN * 4);
  float* r = (float*)take((size_t)BB * NN * 4);
  float* c = (float*)take((size_t)BB * NN * 4);
  float* Lrow = (float*)take((size_t)BB * NN * 4);
  float* Lcol = (float*)take((size_t)BB * NN * 4);   // discarded
  float* xgp = (float*)take((size_t)BB * 4 * DD * 4);
  float* ygp = (float*)take((size_t)BB * 4 * DD * 4);
  float* lossArr = (float*)take(64);
  (void)in_sizes; (void)n_in; (void)out_size; (void)ws_size;

  hipMemsetAsync(ws + zstart, 0, zlen, stream);

  normalize_kernel<<<dim3(2 * BB * NN / 4), dim3(256), 0, stream>>>(X, Y, Xh, Yh);
  transpose_kernel<<<dim3(NN / 64, DD / 64, 2 * BB), dim3(256), 0, stream>>>(X, Y, XT_h,
                                                                             YT_h);
  gemm_a2_kernel<<<dim3(NN / 128, NN / 128, BB), dim3(256), 0, stream>>>(Xh, Yh, A2);
  gemm_a2_kernel<<<dim3(NN / 128, NN / 128, BB), dim3(256), 0, stream>>>(Yh, Xh, A2T);
  for (int it = 0; it < 50; ++it) {
    sink_half_kernel<<<dim3(64, BB), dim3(256), 0, stream>>>(A2, G, F);
    sink_half_kernel<<<dim3(64, BB), dim3(256), 0, stream>>>(A2T, F, G);
  }
  marginals_kernel<<<dim3(8, BB), dim3(512), 0, stream>>>(A2, F, G, r, Lrow);
  marginals_kernel<<<dim3(8, BB), dim3(512), 0, stream>>>(A2T, G, F, c, Lcol);
  bary_mfma_kernel<<<dim3(NN / 64, BB), dim3(256), 0, stream>>>(A2, F, G, r, YT_h, X,
                                                                baryA);
  bary_mfma_kernel<<<dim3(NN / 64, BB), dim3(256), 0, stream>>>(A2T, G, F, c, XT_h, Y,
                                                                baryB);
  xg_kernel<<<dim3(4, BB), dim3(256), 0, stream>>>(X, Y, r, c, xgp, ygp);
  finalize_batch<<<dim3(BB), dim3(256), 0, stream>>>(r, c, Lrow, xgp, ygp, baryA, baryB,
                                                     lossArr);
  final_mean<<<dim3(1), dim3(64), 0, stream>>>(lossArr, out);
}